// Round 6
// baseline (348.402 us; speedup 1.0000x reference)
//
#include <hip/hip_runtime.h>

// MultiHeadHPLSTM — fp32 I/O, bf16 MFMA internal.
// R10 -> R11: both scan-pass kernels rebuilt around wave=chunk autonomy.
// Evidence: R8 (writes -33%) and R10 (occupancy 2x) both left gates_store
// at ~57-60us -> per-wave residency ~25k cyc vs ~3k of work: per-block
// fixed latency (X-load chain, LDS round trip, store drain, barrier, tail)
// with only 64 rows/block to amortize it. Now: 1024 blocks x 4 waves; wave
// w owns chunk blk*4+w (64 rows) in 4 batches of 16, state in registers,
// wave-private LDS slots, ZERO barriers. FGHR (64MB write + 64MB read)
// deleted: pass B recomputes fg/hr bitwise-identically (like og in R7).
// Pass A writes only the 2MB aggregates.

typedef unsigned short ushort;
typedef __bf16 bf16x8 __attribute__((ext_vector_type(8)));
typedef float f32x4 __attribute__((ext_vector_type(4)));

#define CROWS 64
#define NCH  4096
#define NSUP 64

#define GLOAD16(gp, lp) __builtin_amdgcn_global_load_lds( \
    (const __attribute__((address_space(1))) void*)(gp),  \
    (__attribute__((address_space(3))) void*)(lp), 16, 0, 0)

__device__ inline float b2f(ushort u) {
    return __builtin_bit_cast(float, (unsigned)u << 16);
}
__device__ inline ushort f2b(float f) {
    unsigned x = __builtin_bit_cast(unsigned, f);
    x += 0x7FFFu + ((x >> 16) & 1u);   // RNE
    return (ushort)(x >> 16);
}
// divide-free: v_rcp_f32 is 1-ulp, fine for bf16-rounded results
__device__ inline float sigm(float v) { return __builtin_amdgcn_rcpf(1.0f + __expf(-v)); }
__device__ inline float tanh_fast(float v) {
    return 2.0f * __builtin_amdgcn_rcpf(1.0f + __expf(-2.0f * v)) - 1.0f;
}
__device__ inline f32x4 MFMA(bf16x8 a, bf16x8 b, f32x4 c) {
    return __builtin_amdgcn_mfma_f32_16x16x32_bf16(a, b, c, 0, 0, 0);
}

// ---------------- weight prep (fp32 -> transposed bf16) ----------------
__global__ void transpose512(const float* __restrict__ src, ushort* __restrict__ dst) {
    __shared__ float tile[32][33];
    const int tx = threadIdx.x & 31, ty = threadIdx.x >> 5;
    const int x0 = blockIdx.x * 32, y0 = blockIdx.y * 32;
    #pragma unroll
    for (int dy = 0; dy < 32; dy += 8)
        tile[ty + dy][tx] = src[(size_t)(y0 + ty + dy) * 512 + x0 + tx];
    __syncthreads();
    #pragma unroll
    for (int dy = 0; dy < 32; dy += 8)
        dst[(size_t)(x0 + ty + dy) * 512 + y0 + tx] = f2b(tile[tx][ty + dy]);
}

// W2T packed col order: [ig(0..63) | h(64..127) | fg(128..191) | og(192..255)]
__global__ void prep_small(const float* __restrict__ W_gates, const float* __restrict__ W_og,
                           const float* __restrict__ W_c,
                           const float* __restrict__ b_gates, const float* __restrict__ b_og,
                           ushort* __restrict__ W2T, ushort* __restrict__ WcT, float* __restrict__ b2) {
    const int idx = blockIdx.x * 256 + threadIdx.x;
    if (idx < 16384) {
        const int n = idx >> 6, k = idx & 63;
        float v;
        if      (n < 64)  v = W_gates[k * 192 + 64 + n];          // ig
        else if (n < 128) v = W_gates[k * 192 + 128 + (n - 64)];  // h
        else if (n < 192) v = W_gates[k * 192 + (n - 128)];       // fg
        else              v = W_og[k * 64 + (n - 192)];           // og
        W2T[idx] = f2b(v);
    } else if (idx < 16384 + 4096) {
        const int i = idx - 16384;
        const int n = i >> 6, k = i & 63;
        WcT[i] = f2b(W_c[(k << 6) + n]);
    } else if (idx < 16384 + 4096 + 256) {
        const int i = idx - 20480;
        float v;
        if      (i < 64)  v = b_gates[64 + i];
        else if (i < 128) v = b_gates[128 + (i - 64)];
        else if (i < 192) v = b_gates[i - 128];
        else              v = b_og[i - 192];
        b2[i] = v;
    }
}

// fp32 -> bf16 elementwise (inputs pre-convert), 8 elems/thread
__global__ __launch_bounds__(256)
void cvt_f32_bf16(const float* __restrict__ src, ushort* __restrict__ dst) {
    const long i = ((long)blockIdx.x * 256 + threadIdx.x) * 8;
    const float4 v0 = *(const float4*)(src + i);
    const float4 v1 = *(const float4*)(src + i + 4);
    *(ushort4*)(dst + i)     = make_ushort4(f2b(v0.x), f2b(v0.y), f2b(v0.z), f2b(v0.w));
    *(ushort4*)(dst + i + 4) = make_ushort4(f2b(v1.x), f2b(v1.y), f2b(v1.z), f2b(v1.w));
}

// ---------------- big GEMM: C = A(MxK) * Bt(NxK)^T + bias ----------------
template <int BM, int BN, int WAVES_M, int WAVES_N, int A32, int C32>
__global__ __launch_bounds__(256)
void gemm_bt(const void* __restrict__ Av, const ushort* __restrict__ Bt,
             const float* __restrict__ bias, void* __restrict__ Cv,
             int M, int N, int K) {
    constexpr int WM = BM / WAVES_M, WN = BN / WAVES_N;
    constexpr int MT = WM / 16, NT = WN / 16;
    __shared__ __align__(16) ushort sA[BM * 32];
    __shared__ __align__(16) ushort sB[BN * 32];

    const int t = threadIdx.x, w = t >> 6, lane = t & 63;
    const int wm = (w / WAVES_N) * WM, wn = (w % WAVES_N) * WN;
    const long bm = (long)blockIdx.x * BM, bn = (long)blockIdx.y * BN;

    f32x4 acc[MT][NT] = {};

    for (int k0 = 0; k0 < K; k0 += 32) {
        if (A32) {
            const float* A = (const float*)Av;
            #pragma unroll
            for (int is = 0; is < BM / 32; ++is) {
                const int row = is * 32 + (t >> 3);
                const int cd = (t & 7) >> 1, half = t & 1;
                const float4 v = *(const float4*)(A + (bm + row) * (long)K + k0 + (t & 7) * 4);
                *(ushort4*)&sA[row * 32 + ((cd ^ (row & 3)) * 8) + half * 4] =
                    make_ushort4(f2b(v.x), f2b(v.y), f2b(v.z), f2b(v.w));
            }
        } else {
            const ushort* A = (const ushort*)Av;
            #pragma unroll
            for (int is = 0; is < BM / 64; ++is) {
                const int row = t >> 2, kc = t & 3;
                GLOAD16(A + (bm + is * 64 + row) * (long)K + k0 + ((kc ^ (row & 3)) * 8),
                        (char*)sA + is * 4096 + w * 1024);
            }
        }
        #pragma unroll
        for (int is = 0; is < BN / 64; ++is) {
            const int row = t >> 2, kc = t & 3;
            GLOAD16(Bt + (bn + is * 64 + row) * (long)K + k0 + ((kc ^ (row & 3)) * 8),
                    (char*)sB + is * 4096 + w * 1024);
        }
        __syncthreads();

        bf16x8 af[MT], bfr[NT];
        #pragma unroll
        for (int i = 0; i < MT; ++i) {
            const int row = wm + i * 16 + (lane & 15), c = lane >> 4;
            af[i] = *(const bf16x8*)&sA[row * 32 + ((c ^ (row & 3)) * 8)];
        }
        #pragma unroll
        for (int j = 0; j < NT; ++j) {
            const int rb = wn + j * 16 + (lane & 15), c = lane >> 4;
            bfr[j] = *(const bf16x8*)&sB[rb * 32 + ((c ^ (rb & 3)) * 8)];
        }
        #pragma unroll
        for (int i = 0; i < MT; ++i)
            #pragma unroll
            for (int j = 0; j < NT; ++j)
                acc[i][j] = MFMA(af[i], bfr[j], acc[i][j]);
        __syncthreads();
    }

    #pragma unroll
    for (int i = 0; i < MT; ++i)
        #pragma unroll
        for (int j = 0; j < NT; ++j) {
            const long col = bn + wn + j * 16 + (lane & 15);
            const float bv = bias[col];
            #pragma unroll
            for (int r = 0; r < 4; ++r) {
                const long row = bm + wm + i * 16 + ((lane >> 4) << 2) + r;
                const float v = acc[i][j][r] + bv;
                if (C32) ((float*)Cv)[row * (long)N + col] = v;
                else     ((ushort*)Cv)[row * (long)N + col] = f2b(v);
            }
        }
}

// ---------------- pass A: gate GEMM + aggregates only (wave = chunk) ----------------
// Wave w owns chunk blk*4+w (64 rows) in 4 batches of 16. Per batch:
// ig/h/fg GEMM (24 MFMAs) -> activations -> wave-private XOR'd LDS ->
// in-LDS scan (ch=lane) carrying (a,b) in regs. No barriers, no FGHR.
__global__ __launch_bounds__(256, 4)
void gates_agg(const ushort* __restrict__ X, const ushort* __restrict__ W2T,
               const float* __restrict__ b2,
               float* __restrict__ Agg, float* __restrict__ Bgg) {
    __shared__ __align__(16) unsigned sW[4][16 * 64];   // 16 KB, wave-private slots

    const int t = threadIdx.x, w = t >> 6, lane = t & 63;
    const int lr = lane & 15, lc = lane >> 4;
    const long chunk = (long)blockIdx.x * 4 + w;
    const long row0 = chunk * 64;

    float a = 1.0f, b = 0.0f;
    #pragma unroll 1
    for (int bt = 0; bt < 4; ++bt) {
        const long rb = row0 + bt * 16;
        const bf16x8 af0 = *(const bf16x8*)(X + (rb + lr) * 64 + lc * 8);
        const bf16x8 af1 = *(const bf16x8*)(X + (rb + lr) * 64 + 32 + lc * 8);

        #pragma unroll
        for (int g = 0; g < 4; ++g) {
            f32x4 aig = {}, ah = {}, afg = {};
            #pragma unroll
            for (int kk = 0; kk < 2; ++kk) {
                const bf16x8 w0 = *(const bf16x8*)(W2T + (g * 16 + lr) * 64 + kk * 32 + lc * 8);
                const bf16x8 w1 = *(const bf16x8*)(W2T + (64 + g * 16 + lr) * 64 + kk * 32 + lc * 8);
                const bf16x8 w2 = *(const bf16x8*)(W2T + (128 + g * 16 + lr) * 64 + kk * 32 + lc * 8);
                const bf16x8 afk = kk ? af1 : af0;
                aig = MFMA(afk, w0, aig);
                ah  = MFMA(afk, w1, ah);
                afg = MFMA(afk, w2, afg);
            }
            const int ch = g * 16 + lr;
            const float bi = b2[ch], bh = b2[64 + ch], bfg = b2[128 + ch];
            #pragma unroll
            for (int r = 0; r < 4; ++r) {
                const int row = (lc << 2) + r;   // 0..15 local
                const float hr = sigm(aig[r] + bi) * tanh_fast(ah[r] + bh);
                const float fg = sigm(afg[r] + bfg);
                sW[w][row * 64 + (ch ^ (lc << 4))] =
                    (unsigned)f2b(fg) | ((unsigned)f2b(hr) << 16);
            }
        }
        // wave-private scan of this batch, ch = lane; carry (a,b) across batches
        #pragma unroll
        for (int r = 0; r < 16; ++r) {
            const unsigned fh = sW[w][r * 64 + (lane ^ ((r >> 2) << 4))];
            const float fg = b2f((ushort)fh);
            const float hr = b2f((ushort)(fh >> 16));
            a *= fg;
            b = fmaf(b, fg, hr);
        }
    }
    Agg[chunk * 64 + lane] = a;
    Bgg[chunk * 64 + lane] = b;
}

// ---------------- pass B: full gate recompute + apply + PV (wave = chunk) ----------------
// c_in comes straight from prefix arrays (wave = chunk -> no intra-block fold).
// Per batch: ig/h/fg/og GEMM (32 MFMAs) -> transpose via wave-private LDS ->
// apply (c in reg) -> p into swizzled sP -> 16x64 PV GEMM -> O store. No barriers.
__global__ __launch_bounds__(256, 4)
void scan_apply(const ushort* __restrict__ X, const ushort* __restrict__ W2T,
                const float* __restrict__ b2,
                const float* __restrict__ Agg, const float* __restrict__ Bgg,
                const float* __restrict__ PreS,
                const ushort* __restrict__ WcT, const float* __restrict__ b_c,
                ushort* __restrict__ O) {
    __shared__ __align__(16) unsigned sW[4][16 * 64];   // fg|hr (16 KB)
    __shared__ __align__(16) ushort  sOG[4][16 * 64];   // og    (8 KB)
    __shared__ __align__(16) ushort  sP [4][16 * 64];   // p     (8 KB)

    const int t = threadIdx.x, w = t >> 6, lane = t & 63;
    const int lr = lane & 15, lc = lane >> 4;
    const long chunk = (long)blockIdx.x * 4 + w;
    const long row0 = chunk * 64;

    // chunk-incoming c: PreS (super prefix) composed with per-chunk prefix
    float c = fmaf(PreS[(chunk >> 6) * 64 + lane], Agg[chunk * 64 + lane],
                   Bgg[chunk * 64 + lane]);

    const int cch = lane >> 3, half = lane & 7;

    #pragma unroll 1
    for (int bt = 0; bt < 4; ++bt) {
        const long rb = row0 + bt * 16;
        const bf16x8 af0 = *(const bf16x8*)(X + (rb + lr) * 64 + lc * 8);
        const bf16x8 af1 = *(const bf16x8*)(X + (rb + lr) * 64 + 32 + lc * 8);

        #pragma unroll
        for (int g = 0; g < 4; ++g) {
            f32x4 aig = {}, ah = {}, afg = {}, aog = {};
            #pragma unroll
            for (int kk = 0; kk < 2; ++kk) {
                const bf16x8 w0 = *(const bf16x8*)(W2T + (g * 16 + lr) * 64 + kk * 32 + lc * 8);
                const bf16x8 w1 = *(const bf16x8*)(W2T + (64 + g * 16 + lr) * 64 + kk * 32 + lc * 8);
                const bf16x8 w2 = *(const bf16x8*)(W2T + (128 + g * 16 + lr) * 64 + kk * 32 + lc * 8);
                const bf16x8 w3 = *(const bf16x8*)(W2T + (192 + g * 16 + lr) * 64 + kk * 32 + lc * 8);
                const bf16x8 afk = kk ? af1 : af0;
                aig = MFMA(afk, w0, aig);
                ah  = MFMA(afk, w1, ah);
                afg = MFMA(afk, w2, afg);
                aog = MFMA(afk, w3, aog);
            }
            const int ch = g * 16 + lr;
            const float bi = b2[ch], bh = b2[64 + ch];
            const float bfg = b2[128 + ch], bog = b2[192 + ch];
            #pragma unroll
            for (int r = 0; r < 4; ++r) {
                const int row = (lc << 2) + r;
                const float hr = sigm(aig[r] + bi) * tanh_fast(ah[r] + bh);
                const float fg = sigm(afg[r] + bfg);
                const int sl = row * 64 + (ch ^ (lc << 4));
                sW[w][sl]  = (unsigned)f2b(fg) | ((unsigned)f2b(hr) << 16);
                sOG[w][sl] = f2b(sigm(aog[r] + bog));
            }
        }

        // apply: ch = lane over this batch's 16 rows; p = og*c -> swizzled sP
        #pragma unroll
        for (int r = 0; r < 16; ++r) {
            const int sl = r * 64 + (lane ^ ((r >> 2) << 4));
            const unsigned fh = sW[w][sl];
            const float og = b2f(sOG[w][sl]);
            c = fmaf(c, b2f((ushort)fh), b2f((ushort)(fh >> 16)));
            sP[w][r * 64 + ((cch ^ (r & 7)) * 8) + half] = f2b(og * c);
        }

        // PV: p(16x64) @ WcT^T + b_c -> O rows rb..rb+15
        f32x4 acc2[4] = {};
        #pragma unroll
        for (int kk = 0; kk < 2; ++kk) {
            const int cidx = kk * 4 + lc;
            const bf16x8 pa = *(const bf16x8*)&sP[w][lr * 64 + ((cidx ^ (lr & 7)) * 8)];
            #pragma unroll
            for (int j = 0; j < 4; ++j) {
                const bf16x8 wc = *(const bf16x8*)(WcT + (j * 16 + lr) * 64 + kk * 32 + lc * 8);
                acc2[j] = MFMA(pa, wc, acc2[j]);
            }
        }
        #pragma unroll
        for (int j = 0; j < 4; ++j) {
            const int col = j * 16 + lr;
            const float bv = b_c[col];
            #pragma unroll
            for (int r = 0; r < 4; ++r)
                O[(rb + (lc << 2) + r) * 64 + col] = f2b(acc2[j][r] + bv);
        }
    }
}

// ---------------- OLD fused gate GEMM + scan (fallback for small ws) ----------------
template <int APPLY>
__global__ __launch_bounds__(256, 4)
void gates_scan(const ushort* __restrict__ X, const ushort* __restrict__ W2T,
                const float* __restrict__ b2, const ushort* __restrict__ WcT,
                const float* __restrict__ b_c,
                float* __restrict__ Agg, float* __restrict__ Bgg,
                const float* __restrict__ PreS, ushort* __restrict__ O) {
    __shared__ __align__(16) char smem[APPLY ? 35840 : 18432];
    ushort* sFG = (ushort*)smem;
    ushort* sHR = (ushort*)(smem + 9216);
    ushort* sOG = (ushort*)(smem + 18432);
    ushort* sP  = (ushort*)(smem + 27648);

    const int t = threadIdx.x, w = t >> 6, lane = t & 63;
    const int blk = blockIdx.x;
    const long row0 = (long)blk * CROWS;

    const int wm = (w >> 1) * 32;
    const int grpB = w & 1;
    const int colbase = grpB * 128;
    const int lr = lane & 15, lc = lane >> 4;

    bf16x8 af[2][2];
    #pragma unroll
    for (int kk = 0; kk < 2; ++kk)
        #pragma unroll
        for (int i = 0; i < 2; ++i)
            af[kk][i] = *(const bf16x8*)(X + (row0 + wm + i * 16 + lr) * 64 + kk * 32 + lc * 8);

    f32x4 acc[2][8] = {};
    #pragma unroll
    for (int kk = 0; kk < 2; ++kk)
        #pragma unroll
        for (int j = 0; j < 8; ++j) {
            const bf16x8 bf = *(const bf16x8*)(W2T + (colbase + j * 16 + lr) * 64 + kk * 32 + lc * 8);
            acc[0][j] = MFMA(af[kk][0], bf, acc[0][j]);
            acc[1][j] = MFMA(af[kk][1], bf, acc[1][j]);
        }

    if (!grpB) {
        #pragma unroll
        for (int jj = 0; jj < 4; ++jj) {
            const int ch = jj * 16 + lr;
            const float bi = b2[ch], bh = b2[64 + ch];
            #pragma unroll
            for (int i = 0; i < 2; ++i)
                #pragma unroll
                for (int r = 0; r < 4; ++r) {
                    const int row = wm + i * 16 + (lc << 2) + r;
                    const float gi = acc[i][jj][r] + bi;
                    const float gh = acc[i][jj + 4][r] + bh;
                    sHR[row * 72 + ch] = f2b(sigm(gi) * tanh_fast(gh));
                }
        }
    } else {
        #pragma unroll
        for (int jj = 0; jj < 4; ++jj) {
            const int ch = jj * 16 + lr;
            const float bfg = b2[128 + ch], bog = b2[192 + ch];
            #pragma unroll
            for (int i = 0; i < 2; ++i)
                #pragma unroll
                for (int r = 0; r < 4; ++r) {
                    const int row = wm + i * 16 + (lc << 2) + r;
                    sFG[row * 72 + ch] = f2b(sigm(acc[i][jj][r] + bfg));
                    if (APPLY) sOG[row * 72 + ch] = f2b(sigm(acc[i][jj + 4][r] + bog));
                }
        }
    }
    __syncthreads();

    if (!APPLY) {
        if (t < 64) {
            float a = 1.0f, b = 0.0f;
            #pragma unroll 8
            for (int r = 0; r < CROWS; ++r) {
                const float fg = b2f(sFG[r * 72 + t]);
                const float hr = b2f(sHR[r * 72 + t]);
                a *= fg;
                b = fmaf(b, fg, hr);
            }
            Agg[blk * 64 + t] = a;
            Bgg[blk * 64 + t] = b;
        }
        return;
    }

    if (t < 64) {
        float c = fmaf(PreS[(blk >> 6) * 64 + t], Agg[blk * 64 + t], Bgg[blk * 64 + t]);
        const int cch = t >> 3, half = t & 7;
        #pragma unroll 8
        for (int r = 0; r < CROWS; ++r) {
            const float fg = b2f(sFG[r * 72 + t]);
            const float hr = b2f(sHR[r * 72 + t]);
            c = fmaf(c, fg, hr);
            sP[r * 64 + ((cch ^ (r & 7)) * 8) + half] = f2b(b2f(sOG[r * 72 + t]) * c);
        }
    }
    __syncthreads();

    const int wn2 = grpB * 32;
    f32x4 acc2[2][2] = {};
    #pragma unroll
    for (int kk = 0; kk < 2; ++kk) {
        bf16x8 pa[2], wbx[2];
        #pragma unroll
        for (int i = 0; i < 2; ++i) {
            const int row = wm + i * 16 + lr, c = kk * 4 + lc;
            pa[i] = *(const bf16x8*)&sP[row * 64 + ((c ^ (row & 7)) * 8)];
        }
        #pragma unroll
        for (int j = 0; j < 2; ++j)
            wbx[j] = *(const bf16x8*)(WcT + (wn2 + j * 16 + lr) * 64 + kk * 32 + lc * 8);
        #pragma unroll
        for (int i = 0; i < 2; ++i)
            #pragma unroll
            for (int j = 0; j < 2; ++j)
                acc2[i][j] = MFMA(pa[i], wbx[j], acc2[i][j]);
    }
    #pragma unroll
    for (int i = 0; i < 2; ++i)
        #pragma unroll
        for (int j = 0; j < 2; ++j) {
            const int col = wn2 + j * 16 + lr;
            const float bv = b_c[col];
            #pragma unroll
            for (int r = 0; r < 4; ++r) {
                const int row = wm + i * 16 + (lc << 2) + r;
                O[(row0 + row) * 64 + col] = f2b(acc2[i][j][r] + bv);
            }
        }
}

// ---------------- two-level prefix combine ----------------
__global__ void scan_super(float* __restrict__ Agg, float* __restrict__ Bgg,
                           float* __restrict__ SA, float* __restrict__ SB) {
    const int s = blockIdx.x, ch = threadIdx.x;
    float a = 1.0f, b = 0.0f;
    #pragma unroll 8
    for (int j = 0; j < 64; ++j) {
        const int idx = (s * 64 + j) * 64 + ch;
        const float a2 = Agg[idx], bb = Bgg[idx];
        Agg[idx] = a;
        Bgg[idx] = b;
        a *= a2;
        b = fmaf(b, a2, bb);
    }
    SA[s * 64 + ch] = a;
    SB[s * 64 + ch] = b;
}

__global__ void scan_top(const float* __restrict__ SA, const float* __restrict__ SB,
                         float* __restrict__ PreS) {
    const int ch = threadIdx.x;
    float c = 0.0f;
    #pragma unroll 8
    for (int s = 0; s < 64; ++s) {
        PreS[s * 64 + ch] = c;
        c = fmaf(c, SA[s * 64 + ch], SB[s * 64 + ch]);
    }
}

// ---------------- launch ----------------
extern "C" void kernel_launch(void* const* d_in, const int* in_sizes, int n_in,
                              void* d_out, int out_size, void* d_ws, size_t ws_size,
                              hipStream_t stream) {
    const float* inputs  = (const float*)d_in[0];
    const float* W_in    = (const float*)d_in[1];
    const float* b_in    = (const float*)d_in[2];
    const float* W_gates = (const float*)d_in[3];
    const float* b_gates = (const float*)d_in[4];
    const float* W_og    = (const float*)d_in[5];
    const float* b_og    = (const float*)d_in[6];
    const float* W_c     = (const float*)d_in[7];
    const float* b_c     = (const float*)d_in[8];
    const float* W_out   = (const float*)d_in[9];
    const float* b_out   = (const float*)d_in[10];
    float* out = (float*)d_out;

    char* ws = (char*)d_ws;
    ushort* X     = (ushort*)(ws);                   // 33554432 B (O in-place)
    ushort* WinT  = (ushort*)(ws + 33554432);        // 524288
    ushort* WoutT = (ushort*)(ws + 34078720);        // 524288
    ushort* W2T   = (ushort*)(ws + 34603008);        // 32768
    ushort* WcT   = (ushort*)(ws + 34635776);        // 8192
    float*  b2    = (float*)(ws + 34643968);         // 1024
    float*  Agg   = (float*)(ws + 34644992);         // 1048576
    float*  Bgg   = (float*)(ws + 35693568);         // 1048576
    float*  SA    = (float*)(ws + 36742144);         // 16384
    float*  SB    = (float*)(ws + 36758528);         // 16384
    float*  PreS  = (float*)(ws + 36774912);         // 16384
    ushort* Ibf   = (ushort*)(ws + 36791296);        // 33554432
    ushort* O = X;

    const bool big_ws = ws_size >= 70345728ull;      // Ibf end

    transpose512<<<dim3(16, 16), 256, 0, stream>>>(W_in, WinT);
    transpose512<<<dim3(16, 16), 256, 0, stream>>>(W_out, WoutT);
    prep_small<<<81, 256, 0, stream>>>(W_gates, W_og, W_c, b_gates, b_og, W2T, WcT, b2);

    if (big_ws) {
        cvt_f32_bf16<<<8192, 256, 0, stream>>>(inputs, Ibf);
        gemm_bt<128, 128, 2, 2, 0, 0><<<dim3(256, 4), 256, 0, stream>>>(
            Ibf, WinT, b_in, X, 32768, 512, 512);
        gates_agg<<<NCH / 4, 256, 0, stream>>>(X, W2T, b2, Agg, Bgg);
        scan_super<<<NSUP, 64, 0, stream>>>(Agg, Bgg, SA, SB);
        scan_top<<<1, 64, 0, stream>>>(SA, SB, PreS);
        scan_apply<<<NCH / 4, 256, 0, stream>>>(X, W2T, b2, Agg, Bgg, PreS, WcT, b_c, O);
    } else {
        gemm_bt<128, 128, 2, 2, 1, 0><<<dim3(256, 4), 256, 0, stream>>>(
            inputs, WinT, b_in, X, 32768, 512, 512);
        gates_scan<0><<<NCH, 256, 0, stream>>>(X, W2T, b2, WcT, b_c, Agg, Bgg, PreS, O);
        scan_super<<<NSUP, 64, 0, stream>>>(Agg, Bgg, SA, SB);
        scan_top<<<1, 64, 0, stream>>>(SA, SB, PreS);
        gates_scan<1><<<NCH, 256, 0, stream>>>(X, W2T, b2, WcT, b_c, Agg, Bgg, PreS, O);
    }

    gemm_bt<128, 128, 2, 2, 0, 1><<<dim3(256, 4), 256, 0, stream>>>(
        O, WoutT, b_out, out, 32768, 512, 512);
}

// Round 7
// 329.615 us; speedup vs baseline: 1.0570x; 1.0570x over previous
//
#include <hip/hip_runtime.h>

// MultiHeadHPLSTM — fp32 I/O, bf16 MFMA internal.
// R11 -> R12: ONE-TOKEN FIX x2. R11 full-unrolled the channel-group GEMM
// loops ('#pragma unroll' on g) — compiler kept all 4 groups' accumulators
// + pipelined W2T loads live -> >128 regs -> scratch spill (FETCH 247MB,
// WRITE 148MB, first-dispatch 145us warm-up, R7's exact signature).
// Restored '#pragma unroll 1' (R10's proven recipe: one group's 12-16 acc
// regs live at a time). Wave=chunk / zero-barrier / no-FGHR design kept.

typedef unsigned short ushort;
typedef __bf16 bf16x8 __attribute__((ext_vector_type(8)));
typedef float f32x4 __attribute__((ext_vector_type(4)));

#define CROWS 64
#define NCH  4096
#define NSUP 64

#define GLOAD16(gp, lp) __builtin_amdgcn_global_load_lds( \
    (const __attribute__((address_space(1))) void*)(gp),  \
    (__attribute__((address_space(3))) void*)(lp), 16, 0, 0)

__device__ inline float b2f(ushort u) {
    return __builtin_bit_cast(float, (unsigned)u << 16);
}
__device__ inline ushort f2b(float f) {
    unsigned x = __builtin_bit_cast(unsigned, f);
    x += 0x7FFFu + ((x >> 16) & 1u);   // RNE
    return (ushort)(x >> 16);
}
// divide-free: v_rcp_f32 is 1-ulp, fine for bf16-rounded results
__device__ inline float sigm(float v) { return __builtin_amdgcn_rcpf(1.0f + __expf(-v)); }
__device__ inline float tanh_fast(float v) {
    return 2.0f * __builtin_amdgcn_rcpf(1.0f + __expf(-2.0f * v)) - 1.0f;
}
__device__ inline f32x4 MFMA(bf16x8 a, bf16x8 b, f32x4 c) {
    return __builtin_amdgcn_mfma_f32_16x16x32_bf16(a, b, c, 0, 0, 0);
}

// ---------------- weight prep (fp32 -> transposed bf16) ----------------
__global__ void transpose512(const float* __restrict__ src, ushort* __restrict__ dst) {
    __shared__ float tile[32][33];
    const int tx = threadIdx.x & 31, ty = threadIdx.x >> 5;
    const int x0 = blockIdx.x * 32, y0 = blockIdx.y * 32;
    #pragma unroll
    for (int dy = 0; dy < 32; dy += 8)
        tile[ty + dy][tx] = src[(size_t)(y0 + ty + dy) * 512 + x0 + tx];
    __syncthreads();
    #pragma unroll
    for (int dy = 0; dy < 32; dy += 8)
        dst[(size_t)(x0 + ty + dy) * 512 + y0 + tx] = f2b(tile[tx][ty + dy]);
}

// W2T packed col order: [ig(0..63) | h(64..127) | fg(128..191) | og(192..255)]
__global__ void prep_small(const float* __restrict__ W_gates, const float* __restrict__ W_og,
                           const float* __restrict__ W_c,
                           const float* __restrict__ b_gates, const float* __restrict__ b_og,
                           ushort* __restrict__ W2T, ushort* __restrict__ WcT, float* __restrict__ b2) {
    const int idx = blockIdx.x * 256 + threadIdx.x;
    if (idx < 16384) {
        const int n = idx >> 6, k = idx & 63;
        float v;
        if      (n < 64)  v = W_gates[k * 192 + 64 + n];          // ig
        else if (n < 128) v = W_gates[k * 192 + 128 + (n - 64)];  // h
        else if (n < 192) v = W_gates[k * 192 + (n - 128)];       // fg
        else              v = W_og[k * 64 + (n - 192)];           // og
        W2T[idx] = f2b(v);
    } else if (idx < 16384 + 4096) {
        const int i = idx - 16384;
        const int n = i >> 6, k = i & 63;
        WcT[i] = f2b(W_c[(k << 6) + n]);
    } else if (idx < 16384 + 4096 + 256) {
        const int i = idx - 20480;
        float v;
        if      (i < 64)  v = b_gates[64 + i];
        else if (i < 128) v = b_gates[128 + (i - 64)];
        else if (i < 192) v = b_gates[i - 128];
        else              v = b_og[i - 192];
        b2[i] = v;
    }
}

// fp32 -> bf16 elementwise (inputs pre-convert), 8 elems/thread
__global__ __launch_bounds__(256)
void cvt_f32_bf16(const float* __restrict__ src, ushort* __restrict__ dst) {
    const long i = ((long)blockIdx.x * 256 + threadIdx.x) * 8;
    const float4 v0 = *(const float4*)(src + i);
    const float4 v1 = *(const float4*)(src + i + 4);
    *(ushort4*)(dst + i)     = make_ushort4(f2b(v0.x), f2b(v0.y), f2b(v0.z), f2b(v0.w));
    *(ushort4*)(dst + i + 4) = make_ushort4(f2b(v1.x), f2b(v1.y), f2b(v1.z), f2b(v1.w));
}

// ---------------- big GEMM: C = A(MxK) * Bt(NxK)^T + bias ----------------
template <int BM, int BN, int WAVES_M, int WAVES_N, int A32, int C32>
__global__ __launch_bounds__(256)
void gemm_bt(const void* __restrict__ Av, const ushort* __restrict__ Bt,
             const float* __restrict__ bias, void* __restrict__ Cv,
             int M, int N, int K) {
    constexpr int WM = BM / WAVES_M, WN = BN / WAVES_N;
    constexpr int MT = WM / 16, NT = WN / 16;
    __shared__ __align__(16) ushort sA[BM * 32];
    __shared__ __align__(16) ushort sB[BN * 32];

    const int t = threadIdx.x, w = t >> 6, lane = t & 63;
    const int wm = (w / WAVES_N) * WM, wn = (w % WAVES_N) * WN;
    const long bm = (long)blockIdx.x * BM, bn = (long)blockIdx.y * BN;

    f32x4 acc[MT][NT] = {};

    for (int k0 = 0; k0 < K; k0 += 32) {
        if (A32) {
            const float* A = (const float*)Av;
            #pragma unroll
            for (int is = 0; is < BM / 32; ++is) {
                const int row = is * 32 + (t >> 3);
                const int cd = (t & 7) >> 1, half = t & 1;
                const float4 v = *(const float4*)(A + (bm + row) * (long)K + k0 + (t & 7) * 4);
                *(ushort4*)&sA[row * 32 + ((cd ^ (row & 3)) * 8) + half * 4] =
                    make_ushort4(f2b(v.x), f2b(v.y), f2b(v.z), f2b(v.w));
            }
        } else {
            const ushort* A = (const ushort*)Av;
            #pragma unroll
            for (int is = 0; is < BM / 64; ++is) {
                const int row = t >> 2, kc = t & 3;
                GLOAD16(A + (bm + is * 64 + row) * (long)K + k0 + ((kc ^ (row & 3)) * 8),
                        (char*)sA + is * 4096 + w * 1024);
            }
        }
        #pragma unroll
        for (int is = 0; is < BN / 64; ++is) {
            const int row = t >> 2, kc = t & 3;
            GLOAD16(Bt + (bn + is * 64 + row) * (long)K + k0 + ((kc ^ (row & 3)) * 8),
                    (char*)sB + is * 4096 + w * 1024);
        }
        __syncthreads();

        bf16x8 af[MT], bfr[NT];
        #pragma unroll
        for (int i = 0; i < MT; ++i) {
            const int row = wm + i * 16 + (lane & 15), c = lane >> 4;
            af[i] = *(const bf16x8*)&sA[row * 32 + ((c ^ (row & 3)) * 8)];
        }
        #pragma unroll
        for (int j = 0; j < NT; ++j) {
            const int rb = wn + j * 16 + (lane & 15), c = lane >> 4;
            bfr[j] = *(const bf16x8*)&sB[rb * 32 + ((c ^ (rb & 3)) * 8)];
        }
        #pragma unroll
        for (int i = 0; i < MT; ++i)
            #pragma unroll
            for (int j = 0; j < NT; ++j)
                acc[i][j] = MFMA(af[i], bfr[j], acc[i][j]);
        __syncthreads();
    }

    #pragma unroll
    for (int i = 0; i < MT; ++i)
        #pragma unroll
        for (int j = 0; j < NT; ++j) {
            const long col = bn + wn + j * 16 + (lane & 15);
            const float bv = bias[col];
            #pragma unroll
            for (int r = 0; r < 4; ++r) {
                const long row = bm + wm + i * 16 + ((lane >> 4) << 2) + r;
                const float v = acc[i][j][r] + bv;
                if (C32) ((float*)Cv)[row * (long)N + col] = v;
                else     ((ushort*)Cv)[row * (long)N + col] = f2b(v);
            }
        }
}

// ---------------- pass A: gate GEMM + aggregates only (wave = chunk) ----------------
// Wave w owns chunk blk*4+w (64 rows) in 4 batches of 16. Per batch:
// ig/h/fg GEMM (unroll 1 per group: 3 accs live) -> activations ->
// wave-private XOR'd LDS -> in-LDS scan carrying (a,b) in regs. No barriers.
__global__ __launch_bounds__(256, 4)
void gates_agg(const ushort* __restrict__ X, const ushort* __restrict__ W2T,
               const float* __restrict__ b2,
               float* __restrict__ Agg, float* __restrict__ Bgg) {
    __shared__ __align__(16) unsigned sW[4][16 * 64];   // 16 KB, wave-private slots

    const int t = threadIdx.x, w = t >> 6, lane = t & 63;
    const int lr = lane & 15, lc = lane >> 4;
    const long chunk = (long)blockIdx.x * 4 + w;
    const long row0 = chunk * 64;

    float a = 1.0f, b = 0.0f;
    #pragma unroll 1
    for (int bt = 0; bt < 4; ++bt) {
        const long rb = row0 + bt * 16;
        const bf16x8 af0 = *(const bf16x8*)(X + (rb + lr) * 64 + lc * 8);
        const bf16x8 af1 = *(const bf16x8*)(X + (rb + lr) * 64 + 32 + lc * 8);

        #pragma unroll 1
        for (int g = 0; g < 4; ++g) {
            f32x4 aig = {}, ah = {}, afg = {};
            #pragma unroll
            for (int kk = 0; kk < 2; ++kk) {
                const bf16x8 w0 = *(const bf16x8*)(W2T + (g * 16 + lr) * 64 + kk * 32 + lc * 8);
                const bf16x8 w1 = *(const bf16x8*)(W2T + (64 + g * 16 + lr) * 64 + kk * 32 + lc * 8);
                const bf16x8 w2 = *(const bf16x8*)(W2T + (128 + g * 16 + lr) * 64 + kk * 32 + lc * 8);
                const bf16x8 afk = kk ? af1 : af0;
                aig = MFMA(afk, w0, aig);
                ah  = MFMA(afk, w1, ah);
                afg = MFMA(afk, w2, afg);
            }
            const int ch = g * 16 + lr;
            const float bi = b2[ch], bh = b2[64 + ch], bfg = b2[128 + ch];
            #pragma unroll
            for (int r = 0; r < 4; ++r) {
                const int row = (lc << 2) + r;   // 0..15 local
                const float hr = sigm(aig[r] + bi) * tanh_fast(ah[r] + bh);
                const float fg = sigm(afg[r] + bfg);
                sW[w][row * 64 + (ch ^ (lc << 4))] =
                    (unsigned)f2b(fg) | ((unsigned)f2b(hr) << 16);
            }
        }
        // wave-private scan of this batch, ch = lane; carry (a,b) across batches
        #pragma unroll
        for (int r = 0; r < 16; ++r) {
            const unsigned fh = sW[w][r * 64 + (lane ^ ((r >> 2) << 4))];
            const float fg = b2f((ushort)fh);
            const float hr = b2f((ushort)(fh >> 16));
            a *= fg;
            b = fmaf(b, fg, hr);
        }
    }
    Agg[chunk * 64 + lane] = a;
    Bgg[chunk * 64 + lane] = b;
}

// ---------------- pass B: full gate recompute + apply + PV (wave = chunk) ----------------
// c_in comes straight from prefix arrays (wave = chunk -> no intra-block fold).
// Per batch: ig/h/fg/og GEMM (unroll 1 per group: 4 accs live) -> transpose
// via wave-private LDS -> apply (c in reg) -> p into swizzled sP ->
// 16x64 PV GEMM -> O store. No barriers.
__global__ __launch_bounds__(256, 4)
void scan_apply(const ushort* __restrict__ X, const ushort* __restrict__ W2T,
                const float* __restrict__ b2,
                const float* __restrict__ Agg, const float* __restrict__ Bgg,
                const float* __restrict__ PreS,
                const ushort* __restrict__ WcT, const float* __restrict__ b_c,
                ushort* __restrict__ O) {
    __shared__ __align__(16) unsigned sW[4][16 * 64];   // fg|hr (16 KB)
    __shared__ __align__(16) ushort  sOG[4][16 * 64];   // og    (8 KB)
    __shared__ __align__(16) ushort  sP [4][16 * 64];   // p     (8 KB)

    const int t = threadIdx.x, w = t >> 6, lane = t & 63;
    const int lr = lane & 15, lc = lane >> 4;
    const long chunk = (long)blockIdx.x * 4 + w;
    const long row0 = chunk * 64;

    // chunk-incoming c: PreS (super prefix) composed with per-chunk prefix
    float c = fmaf(PreS[(chunk >> 6) * 64 + lane], Agg[chunk * 64 + lane],
                   Bgg[chunk * 64 + lane]);

    const int cch = lane >> 3, half = lane & 7;

    #pragma unroll 1
    for (int bt = 0; bt < 4; ++bt) {
        const long rb = row0 + bt * 16;
        const bf16x8 af0 = *(const bf16x8*)(X + (rb + lr) * 64 + lc * 8);
        const bf16x8 af1 = *(const bf16x8*)(X + (rb + lr) * 64 + 32 + lc * 8);

        #pragma unroll 1
        for (int g = 0; g < 4; ++g) {
            f32x4 aig = {}, ah = {}, afg = {}, aog = {};
            #pragma unroll
            for (int kk = 0; kk < 2; ++kk) {
                const bf16x8 w0 = *(const bf16x8*)(W2T + (g * 16 + lr) * 64 + kk * 32 + lc * 8);
                const bf16x8 w1 = *(const bf16x8*)(W2T + (64 + g * 16 + lr) * 64 + kk * 32 + lc * 8);
                const bf16x8 w2 = *(const bf16x8*)(W2T + (128 + g * 16 + lr) * 64 + kk * 32 + lc * 8);
                const bf16x8 w3 = *(const bf16x8*)(W2T + (192 + g * 16 + lr) * 64 + kk * 32 + lc * 8);
                const bf16x8 afk = kk ? af1 : af0;
                aig = MFMA(afk, w0, aig);
                ah  = MFMA(afk, w1, ah);
                afg = MFMA(afk, w2, afg);
                aog = MFMA(afk, w3, aog);
            }
            const int ch = g * 16 + lr;
            const float bi = b2[ch], bh = b2[64 + ch];
            const float bfg = b2[128 + ch], bog = b2[192 + ch];
            #pragma unroll
            for (int r = 0; r < 4; ++r) {
                const int row = (lc << 2) + r;
                const float hr = sigm(aig[r] + bi) * tanh_fast(ah[r] + bh);
                const float fg = sigm(afg[r] + bfg);
                const int sl = row * 64 + (ch ^ (lc << 4));
                sW[w][sl]  = (unsigned)f2b(fg) | ((unsigned)f2b(hr) << 16);
                sOG[w][sl] = f2b(sigm(aog[r] + bog));
            }
        }

        // apply: ch = lane over this batch's 16 rows; p = og*c -> swizzled sP
        #pragma unroll
        for (int r = 0; r < 16; ++r) {
            const int sl = r * 64 + (lane ^ ((r >> 2) << 4));
            const unsigned fh = sW[w][sl];
            const float og = b2f(sOG[w][sl]);
            c = fmaf(c, b2f((ushort)fh), b2f((ushort)(fh >> 16)));
            sP[w][r * 64 + ((cch ^ (r & 7)) * 8) + half] = f2b(og * c);
        }

        // PV: p(16x64) @ WcT^T + b_c -> O rows rb..rb+15
        f32x4 acc2[4] = {};
        #pragma unroll
        for (int kk = 0; kk < 2; ++kk) {
            const int cidx = kk * 4 + lc;
            const bf16x8 pa = *(const bf16x8*)&sP[w][lr * 64 + ((cidx ^ (lr & 7)) * 8)];
            #pragma unroll
            for (int j = 0; j < 4; ++j) {
                const bf16x8 wc = *(const bf16x8*)(WcT + (j * 16 + lr) * 64 + kk * 32 + lc * 8);
                acc2[j] = MFMA(pa, wc, acc2[j]);
            }
        }
        #pragma unroll
        for (int j = 0; j < 4; ++j) {
            const int col = j * 16 + lr;
            const float bv = b_c[col];
            #pragma unroll
            for (int r = 0; r < 4; ++r)
                O[(rb + (lc << 2) + r) * 64 + col] = f2b(acc2[j][r] + bv);
        }
    }
}

// ---------------- OLD fused gate GEMM + scan (fallback for small ws) ----------------
template <int APPLY>
__global__ __launch_bounds__(256, 4)
void gates_scan(const ushort* __restrict__ X, const ushort* __restrict__ W2T,
                const float* __restrict__ b2, const ushort* __restrict__ WcT,
                const float* __restrict__ b_c,
                float* __restrict__ Agg, float* __restrict__ Bgg,
                const float* __restrict__ PreS, ushort* __restrict__ O) {
    __shared__ __align__(16) char smem[APPLY ? 35840 : 18432];
    ushort* sFG = (ushort*)smem;
    ushort* sHR = (ushort*)(smem + 9216);
    ushort* sOG = (ushort*)(smem + 18432);
    ushort* sP  = (ushort*)(smem + 27648);

    const int t = threadIdx.x, w = t >> 6, lane = t & 63;
    const int blk = blockIdx.x;
    const long row0 = (long)blk * CROWS;

    const int wm = (w >> 1) * 32;
    const int grpB = w & 1;
    const int colbase = grpB * 128;
    const int lr = lane & 15, lc = lane >> 4;

    bf16x8 af[2][2];
    #pragma unroll
    for (int kk = 0; kk < 2; ++kk)
        #pragma unroll
        for (int i = 0; i < 2; ++i)
            af[kk][i] = *(const bf16x8*)(X + (row0 + wm + i * 16 + lr) * 64 + kk * 32 + lc * 8);

    f32x4 acc[2][8] = {};
    #pragma unroll
    for (int kk = 0; kk < 2; ++kk)
        #pragma unroll
        for (int j = 0; j < 8; ++j) {
            const bf16x8 bf = *(const bf16x8*)(W2T + (colbase + j * 16 + lr) * 64 + kk * 32 + lc * 8);
            acc[0][j] = MFMA(af[kk][0], bf, acc[0][j]);
            acc[1][j] = MFMA(af[kk][1], bf, acc[1][j]);
        }

    if (!grpB) {
        #pragma unroll
        for (int jj = 0; jj < 4; ++jj) {
            const int ch = jj * 16 + lr;
            const float bi = b2[ch], bh = b2[64 + ch];
            #pragma unroll
            for (int i = 0; i < 2; ++i)
                #pragma unroll
                for (int r = 0; r < 4; ++r) {
                    const int row = wm + i * 16 + (lc << 2) + r;
                    const float gi = acc[i][jj][r] + bi;
                    const float gh = acc[i][jj + 4][r] + bh;
                    sHR[row * 72 + ch] = f2b(sigm(gi) * tanh_fast(gh));
                }
        }
    } else {
        #pragma unroll
        for (int jj = 0; jj < 4; ++jj) {
            const int ch = jj * 16 + lr;
            const float bfg = b2[128 + ch], bog = b2[192 + ch];
            #pragma unroll
            for (int i = 0; i < 2; ++i)
                #pragma unroll
                for (int r = 0; r < 4; ++r) {
                    const int row = wm + i * 16 + (lc << 2) + r;
                    sFG[row * 72 + ch] = f2b(sigm(acc[i][jj][r] + bfg));
                    if (APPLY) sOG[row * 72 + ch] = f2b(sigm(acc[i][jj + 4][r] + bog));
                }
        }
    }
    __syncthreads();

    if (!APPLY) {
        if (t < 64) {
            float a = 1.0f, b = 0.0f;
            #pragma unroll 8
            for (int r = 0; r < CROWS; ++r) {
                const float fg = b2f(sFG[r * 72 + t]);
                const float hr = b2f(sHR[r * 72 + t]);
                a *= fg;
                b = fmaf(b, fg, hr);
            }
            Agg[blk * 64 + t] = a;
            Bgg[blk * 64 + t] = b;
        }
        return;
    }

    if (t < 64) {
        float c = fmaf(PreS[(blk >> 6) * 64 + t], Agg[blk * 64 + t], Bgg[blk * 64 + t]);
        const int cch = t >> 3, half = t & 7;
        #pragma unroll 8
        for (int r = 0; r < CROWS; ++r) {
            const float fg = b2f(sFG[r * 72 + t]);
            const float hr = b2f(sHR[r * 72 + t]);
            c = fmaf(c, fg, hr);
            sP[r * 64 + ((cch ^ (r & 7)) * 8) + half] = f2b(b2f(sOG[r * 72 + t]) * c);
        }
    }
    __syncthreads();

    const int wn2 = grpB * 32;
    f32x4 acc2[2][2] = {};
    #pragma unroll
    for (int kk = 0; kk < 2; ++kk) {
        bf16x8 pa[2], wbx[2];
        #pragma unroll
        for (int i = 0; i < 2; ++i) {
            const int row = wm + i * 16 + lr, c = kk * 4 + lc;
            pa[i] = *(const bf16x8*)&sP[row * 64 + ((c ^ (row & 7)) * 8)];
        }
        #pragma unroll
        for (int j = 0; j < 2; ++j)
            wbx[j] = *(const bf16x8*)(WcT + (wn2 + j * 16 + lr) * 64 + kk * 32 + lc * 8);
        #pragma unroll
        for (int i = 0; i < 2; ++i)
            #pragma unroll
            for (int j = 0; j < 2; ++j)
                acc2[i][j] = MFMA(pa[i], wbx[j], acc2[i][j]);
    }
    #pragma unroll
    for (int i = 0; i < 2; ++i)
        #pragma unroll
        for (int j = 0; j < 2; ++j) {
            const int col = wn2 + j * 16 + lr;
            const float bv = b_c[col];
            #pragma unroll
            for (int r = 0; r < 4; ++r) {
                const int row = wm + i * 16 + (lc << 2) + r;
                O[(row0 + row) * 64 + col] = f2b(acc2[i][j][r] + bv);
            }
        }
}

// ---------------- two-level prefix combine ----------------
__global__ void scan_super(float* __restrict__ Agg, float* __restrict__ Bgg,
                           float* __restrict__ SA, float* __restrict__ SB) {
    const int s = blockIdx.x, ch = threadIdx.x;
    float a = 1.0f, b = 0.0f;
    #pragma unroll 8
    for (int j = 0; j < 64; ++j) {
        const int idx = (s * 64 + j) * 64 + ch;
        const float a2 = Agg[idx], bb = Bgg[idx];
        Agg[idx] = a;
        Bgg[idx] = b;
        a *= a2;
        b = fmaf(b, a2, bb);
    }
    SA[s * 64 + ch] = a;
    SB[s * 64 + ch] = b;
}

__global__ void scan_top(const float* __restrict__ SA, const float* __restrict__ SB,
                         float* __restrict__ PreS) {
    const int ch = threadIdx.x;
    float c = 0.0f;
    #pragma unroll 8
    for (int s = 0; s < 64; ++s) {
        PreS[s * 64 + ch] = c;
        c = fmaf(c, SA[s * 64 + ch], SB[s * 64 + ch]);
    }
}

// ---------------- launch ----------------
extern "C" void kernel_launch(void* const* d_in, const int* in_sizes, int n_in,
                              void* d_out, int out_size, void* d_ws, size_t ws_size,
                              hipStream_t stream) {
    const float* inputs  = (const float*)d_in[0];
    const float* W_in    = (const float*)d_in[1];
    const float* b_in    = (const float*)d_in[2];
    const float* W_gates = (const float*)d_in[3];
    const float* b_gates = (const float*)d_in[4];
    const float* W_og    = (const float*)d_in[5];
    const float* b_og    = (const float*)d_in[6];
    const float* W_c     = (const float*)d_in[7];
    const float* b_c     = (const float*)d_in[8];
    const float* W_out   = (const float*)d_in[9];
    const float* b_out   = (const float*)d_in[10];
    float* out = (float*)d_out;

    char* ws = (char*)d_ws;
    ushort* X     = (ushort*)(ws);                   // 33554432 B (O in-place)
    ushort* WinT  = (ushort*)(ws + 33554432);        // 524288
    ushort* WoutT = (ushort*)(ws + 34078720);        // 524288
    ushort* W2T   = (ushort*)(ws + 34603008);        // 32768
    ushort* WcT   = (ushort*)(ws + 34635776);        // 8192
    float*  b2    = (float*)(ws + 34643968);         // 1024
    float*  Agg   = (float*)(ws + 34644992);         // 1048576
    float*  Bgg   = (float*)(ws + 35693568);         // 1048576
    float*  SA    = (float*)(ws + 36742144);         // 16384
    float*  SB    = (float*)(ws + 36758528);         // 16384
    float*  PreS  = (float*)(ws + 36774912);         // 16384
    ushort* Ibf   = (ushort*)(ws + 36791296);        // 33554432
    ushort* O = X;

    const bool big_ws = ws_size >= 70345728ull;      // Ibf end

    transpose512<<<dim3(16, 16), 256, 0, stream>>>(W_in, WinT);
    transpose512<<<dim3(16, 16), 256, 0, stream>>>(W_out, WoutT);
    prep_small<<<81, 256, 0, stream>>>(W_gates, W_og, W_c, b_gates, b_og, W2T, WcT, b2);

    if (big_ws) {
        cvt_f32_bf16<<<8192, 256, 0, stream>>>(inputs, Ibf);
        gemm_bt<128, 128, 2, 2, 0, 0><<<dim3(256, 4), 256, 0, stream>>>(
            Ibf, WinT, b_in, X, 32768, 512, 512);
        gates_agg<<<NCH / 4, 256, 0, stream>>>(X, W2T, b2, Agg, Bgg);
        scan_super<<<NSUP, 64, 0, stream>>>(Agg, Bgg, SA, SB);
        scan_top<<<1, 64, 0, stream>>>(SA, SB, PreS);
        scan_apply<<<NCH / 4, 256, 0, stream>>>(X, W2T, b2, Agg, Bgg, PreS, WcT, b_c, O);
    } else {
        gemm_bt<128, 128, 2, 2, 1, 0><<<dim3(256, 4), 256, 0, stream>>>(
            inputs, WinT, b_in, X, 32768, 512, 512);
        gates_scan<0><<<NCH, 256, 0, stream>>>(X, W2T, b2, WcT, b_c, Agg, Bgg, PreS, O);
        scan_super<<<NSUP, 64, 0, stream>>>(Agg, Bgg, SA, SB);
        scan_top<<<1, 64, 0, stream>>>(SA, SB, PreS);
        gates_scan<1><<<NCH, 256, 0, stream>>>(X, W2T, b2, WcT, b_c, Agg, Bgg, PreS, O);
    }

    gemm_bt<128, 128, 2, 2, 0, 1><<<dim3(256, 4), 256, 0, stream>>>(
        O, WoutT, b_out, out, 32768, 512, 512);
}

// Round 8
// 310.559 us; speedup vs baseline: 1.1219x; 1.0614x over previous
//
#include <hip/hip_runtime.h>

// MultiHeadHPLSTM — fp32 I/O, bf16 MFMA internal.
// R12 -> R13: single-pass fused scan with decoupled lookback.
// Arithmetic: activations are transcendental-bound (8 trans/elem x 134.2M
// = 1.07G ops ~= 55us floor at quarter-rate) — explains the 56-60us
// gates_store plateau across R6/R8/R9/R10. This round: (a) compute each
// activation ONCE in a single kernel (gate GEMM -> act -> segmented scan
// -> per-channel lookback over packed u64 agent atomics [value+validity in
// one word, no fences, rocPRIM-style] -> apply -> PV -> O), replacing
// gates_store+scan_super+scan_top+scan_apply; (b) trans fusion: hr =
// (1-B)*rcp((1+A)(1+B)) and fg/og share one rcp -> 6 trans/elem (~41us
// floor, one kernel). All GEMM/LDS/swizzle building blocks verbatim R6.

typedef unsigned short ushort;
typedef __bf16 bf16x8 __attribute__((ext_vector_type(8)));
typedef float f32x4 __attribute__((ext_vector_type(4)));

#define CROWS 64
#define NCH  4096
#define NSUP 64
#define EMPTY64 0xFFFFFFFFFFFFFFFFull

#define GLOAD16(gp, lp) __builtin_amdgcn_global_load_lds( \
    (const __attribute__((address_space(1))) void*)(gp),  \
    (__attribute__((address_space(3))) void*)(lp), 16, 0, 0)

__device__ inline float b2f(ushort u) {
    return __builtin_bit_cast(float, (unsigned)u << 16);
}
__device__ inline ushort f2b(float f) {
    unsigned x = __builtin_bit_cast(unsigned, f);
    x += 0x7FFFu + ((x >> 16) & 1u);   // RNE
    return (ushort)(x >> 16);
}
// divide-free: v_rcp_f32 is 1-ulp, fine for bf16-rounded results
__device__ inline float sigm(float v) { return __builtin_amdgcn_rcpf(1.0f + __expf(-v)); }
__device__ inline float tanh_fast(float v) {
    return 2.0f * __builtin_amdgcn_rcpf(1.0f + __expf(-2.0f * v)) - 1.0f;
}
__device__ inline f32x4 MFMA(bf16x8 a, bf16x8 b, f32x4 c) {
    return __builtin_amdgcn_mfma_f32_16x16x32_bf16(a, b, c, 0, 0, 0);
}

// ---------------- weight prep (fp32 -> transposed bf16) ----------------
__global__ void transpose512(const float* __restrict__ src, ushort* __restrict__ dst) {
    __shared__ float tile[32][33];
    const int tx = threadIdx.x & 31, ty = threadIdx.x >> 5;
    const int x0 = blockIdx.x * 32, y0 = blockIdx.y * 32;
    #pragma unroll
    for (int dy = 0; dy < 32; dy += 8)
        tile[ty + dy][tx] = src[(size_t)(y0 + ty + dy) * 512 + x0 + tx];
    __syncthreads();
    #pragma unroll
    for (int dy = 0; dy < 32; dy += 8)
        dst[(size_t)(x0 + ty + dy) * 512 + y0 + tx] = f2b(tile[tx][ty + dy]);
}

// W2T packed col order: [ig(0..63) | h(64..127) | fg(128..191) | og(192..255)]
__global__ void prep_small(const float* __restrict__ W_gates, const float* __restrict__ W_og,
                           const float* __restrict__ W_c,
                           const float* __restrict__ b_gates, const float* __restrict__ b_og,
                           ushort* __restrict__ W2T, ushort* __restrict__ WcT, float* __restrict__ b2) {
    const int idx = blockIdx.x * 256 + threadIdx.x;
    if (idx < 16384) {
        const int n = idx >> 6, k = idx & 63;
        float v;
        if      (n < 64)  v = W_gates[k * 192 + 64 + n];          // ig
        else if (n < 128) v = W_gates[k * 192 + 128 + (n - 64)];  // h
        else if (n < 192) v = W_gates[k * 192 + (n - 128)];       // fg
        else              v = W_og[k * 64 + (n - 192)];           // og
        W2T[idx] = f2b(v);
    } else if (idx < 16384 + 4096) {
        const int i = idx - 16384;
        const int n = i >> 6, k = i & 63;
        WcT[i] = f2b(W_c[(k << 6) + n]);
    } else if (idx < 16384 + 4096 + 256) {
        const int i = idx - 20480;
        float v;
        if      (i < 64)  v = b_gates[64 + i];
        else if (i < 128) v = b_gates[128 + (i - 64)];
        else if (i < 192) v = b_gates[i - 128];
        else              v = b_og[i - 192];
        b2[i] = v;
    }
}

// fp32 -> bf16 elementwise (inputs pre-convert), 8 elems/thread.
// Also (re)initializes the lookback state arrays to EMPTY each launch.
__global__ __launch_bounds__(256)
void cvt_f32_bf16(const float* __restrict__ src, ushort* __restrict__ dst,
                  unsigned long long* __restrict__ P1, unsigned long long* __restrict__ P2) {
    const int j = blockIdx.x * 256 + threadIdx.x;
    if (P1 != nullptr && j < NCH * 64) { P1[j] = EMPTY64; P2[j] = EMPTY64; }
    const long i = ((long)blockIdx.x * 256 + threadIdx.x) * 8;
    const float4 v0 = *(const float4*)(src + i);
    const float4 v1 = *(const float4*)(src + i + 4);
    *(ushort4*)(dst + i)     = make_ushort4(f2b(v0.x), f2b(v0.y), f2b(v0.z), f2b(v0.w));
    *(ushort4*)(dst + i + 4) = make_ushort4(f2b(v1.x), f2b(v1.y), f2b(v1.z), f2b(v1.w));
}

// ---------------- big GEMM: C = A(MxK) * Bt(NxK)^T + bias ----------------
template <int BM, int BN, int WAVES_M, int WAVES_N, int A32, int C32>
__global__ __launch_bounds__(256)
void gemm_bt(const void* __restrict__ Av, const ushort* __restrict__ Bt,
             const float* __restrict__ bias, void* __restrict__ Cv,
             int M, int N, int K) {
    constexpr int WM = BM / WAVES_M, WN = BN / WAVES_N;
    constexpr int MT = WM / 16, NT = WN / 16;
    __shared__ __align__(16) ushort sA[BM * 32];
    __shared__ __align__(16) ushort sB[BN * 32];

    const int t = threadIdx.x, w = t >> 6, lane = t & 63;
    const int wm = (w / WAVES_N) * WM, wn = (w % WAVES_N) * WN;
    const long bm = (long)blockIdx.x * BM, bn = (long)blockIdx.y * BN;

    f32x4 acc[MT][NT] = {};

    for (int k0 = 0; k0 < K; k0 += 32) {
        if (A32) {
            const float* A = (const float*)Av;
            #pragma unroll
            for (int is = 0; is < BM / 32; ++is) {
                const int row = is * 32 + (t >> 3);
                const int cd = (t & 7) >> 1, half = t & 1;
                const float4 v = *(const float4*)(A + (bm + row) * (long)K + k0 + (t & 7) * 4);
                *(ushort4*)&sA[row * 32 + ((cd ^ (row & 3)) * 8) + half * 4] =
                    make_ushort4(f2b(v.x), f2b(v.y), f2b(v.z), f2b(v.w));
            }
        } else {
            const ushort* A = (const ushort*)Av;
            #pragma unroll
            for (int is = 0; is < BM / 64; ++is) {
                const int row = t >> 2, kc = t & 3;
                GLOAD16(A + (bm + is * 64 + row) * (long)K + k0 + ((kc ^ (row & 3)) * 8),
                        (char*)sA + is * 4096 + w * 1024);
            }
        }
        #pragma unroll
        for (int is = 0; is < BN / 64; ++is) {
            const int row = t >> 2, kc = t & 3;
            GLOAD16(Bt + (bn + is * 64 + row) * (long)K + k0 + ((kc ^ (row & 3)) * 8),
                    (char*)sB + is * 4096 + w * 1024);
        }
        __syncthreads();

        bf16x8 af[MT], bfr[NT];
        #pragma unroll
        for (int i = 0; i < MT; ++i) {
            const int row = wm + i * 16 + (lane & 15), c = lane >> 4;
            af[i] = *(const bf16x8*)&sA[row * 32 + ((c ^ (row & 3)) * 8)];
        }
        #pragma unroll
        for (int j = 0; j < NT; ++j) {
            const int rb = wn + j * 16 + (lane & 15), c = lane >> 4;
            bfr[j] = *(const bf16x8*)&sB[rb * 32 + ((c ^ (rb & 3)) * 8)];
        }
        #pragma unroll
        for (int i = 0; i < MT; ++i)
            #pragma unroll
            for (int j = 0; j < NT; ++j)
                acc[i][j] = MFMA(af[i], bfr[j], acc[i][j]);
        __syncthreads();
    }

    #pragma unroll
    for (int i = 0; i < MT; ++i)
        #pragma unroll
        for (int j = 0; j < NT; ++j) {
            const long col = bn + wn + j * 16 + (lane & 15);
            const float bv = bias[col];
            #pragma unroll
            for (int r = 0; r < 4; ++r) {
                const long row = bm + wm + i * 16 + ((lane >> 4) << 2) + r;
                const float v = acc[i][j][r] + bv;
                if (C32) ((float*)Cv)[row * (long)N + col] = v;
                else     ((ushort*)Cv)[row * (long)N + col] = f2b(v);
            }
        }
}

// ---------------- SINGLE PASS: gates + scan (lookback) + apply + PV ----------------
// R6's proven gates_scan<1> body, plus: fused-rcp activations (6 trans/elem),
// 4-wave segmented partials, and decoupled lookback over packed u64 agent
// atomics (low32 = a / flag word, high32 = b / value): value+validity are
// one atomic word -> no fences needed. Block 0 publishes inclusive first;
// in-order HW dispatch guarantees predecessors are scheduled (rocPRIM model).
__global__ __launch_bounds__(256, 4)
void gates_fused(const ushort* __restrict__ X, const ushort* __restrict__ W2T,
                 const float* __restrict__ b2, const ushort* __restrict__ WcT,
                 const float* __restrict__ b_c,
                 unsigned long long* __restrict__ Ppart,
                 unsigned long long* __restrict__ Pincl,
                 ushort* __restrict__ O) {
    __shared__ __align__(16) char smem[38400];
    ushort* sFG = (ushort*)smem;                    // 64x72  (9216)
    ushort* sHR = (ushort*)(smem + 9216);           // 64x72
    ushort* sOG = (ushort*)(smem + 18432);          // 64x72
    ushort* sP  = (ushort*)(smem + 27648);          // 64x64 swizzled (8192)
    float*  spa = (float*)(smem + 35840);           // [4][64]
    float*  spb = (float*)(smem + 36864);           // [4][64]
    float*  sCin= (float*)(smem + 37888);           // [64]

    const int t = threadIdx.x, w = t >> 6, lane = t & 63;
    const int blk = blockIdx.x;
    const long row0 = (long)blk * CROWS;

    const int wm = (w >> 1) * 32;
    const int grpB = w & 1;
    const int colbase = grpB * 128;
    const int lr = lane & 15, lc = lane >> 4;

    // gate GEMM (verbatim R6): grpA -> [ig|h], grpB -> [fg|og]
    bf16x8 af[2][2];
    #pragma unroll
    for (int kk = 0; kk < 2; ++kk)
        #pragma unroll
        for (int i = 0; i < 2; ++i)
            af[kk][i] = *(const bf16x8*)(X + (row0 + wm + i * 16 + lr) * 64 + kk * 32 + lc * 8);

    f32x4 acc[2][8] = {};
    #pragma unroll
    for (int kk = 0; kk < 2; ++kk)
        #pragma unroll
        for (int j = 0; j < 8; ++j) {
            const bf16x8 bf = *(const bf16x8*)(W2T + (colbase + j * 16 + lr) * 64 + kk * 32 + lc * 8);
            acc[0][j] = MFMA(af[kk][0], bf, acc[0][j]);
            acc[1][j] = MFMA(af[kk][1], bf, acc[1][j]);
        }

    // activations with shared-rcp fusion (3 trans per elem per wave-group)
    if (!grpB) {
        #pragma unroll
        for (int jj = 0; jj < 4; ++jj) {
            const int ch = jj * 16 + lr;
            const float bi = b2[ch], bh = b2[64 + ch];
            #pragma unroll
            for (int i = 0; i < 2; ++i)
                #pragma unroll
                for (int r = 0; r < 4; ++r) {
                    const int row = wm + i * 16 + (lc << 2) + r;
                    const float gi = acc[i][jj][r] + bi;
                    const float gh = acc[i][jj + 4][r] + bh;
                    // hr = sigm(gi)*tanh(gh) = (1-B) / ((1+A)(1+B))
                    const float A = __expf(-gi);
                    const float B = __expf(-2.0f * gh);
                    const float hr = (1.0f - B) * __builtin_amdgcn_rcpf((1.0f + A) * (1.0f + B));
                    sHR[row * 72 + ch] = f2b(hr);
                }
        }
    } else {
        #pragma unroll
        for (int jj = 0; jj < 4; ++jj) {
            const int ch = jj * 16 + lr;
            const float bfg = b2[128 + ch], bog = b2[192 + ch];
            #pragma unroll
            for (int i = 0; i < 2; ++i)
                #pragma unroll
                for (int r = 0; r < 4; ++r) {
                    const int row = wm + i * 16 + (lc << 2) + r;
                    // fg = 1/(1+C), og = 1/(1+D) via one rcp of the product
                    const float C = __expf(-(acc[i][jj][r] + bfg));
                    const float D = __expf(-(acc[i][jj + 4][r] + bog));
                    const float R = __builtin_amdgcn_rcpf((1.0f + C) * (1.0f + D));
                    sFG[row * 72 + ch] = f2b((1.0f + D) * R);
                    sOG[row * 72 + ch] = f2b((1.0f + C) * R);
                }
        }
    }
    __syncthreads();

    // 4-wave segmented partials (wave w: rows w*16..w*16+15, ch = lane)
    {
        float a = 1.0f, b = 0.0f;
        #pragma unroll
        for (int r = 0; r < 16; ++r) {
            const int row = (w << 4) + r;
            const float fg = b2f(sFG[row * 72 + lane]);
            const float hr = b2f(sHR[row * 72 + lane]);
            a *= fg;
            b = fmaf(b, fg, hr);
        }
        spa[(w << 6) + lane] = a;
        spb[(w << 6) + lane] = b;
    }
    __syncthreads();

    // wave0: combine segments -> publish partial -> lookback -> publish inclusive
    if (t < 64) {
        float a = spa[t], b = spb[t];
        #pragma unroll
        for (int k = 1; k < 4; ++k) {
            const float a2 = spa[(k << 6) + t];
            const float bb = spb[(k << 6) + t];
            a *= a2;
            b = fmaf(b, a2, bb);
        }
        const long me = (long)blk * 64 + t;
        __hip_atomic_store(&Ppart[me],
            ((unsigned long long)__builtin_bit_cast(unsigned, b) << 32) |
             (unsigned long long)__builtin_bit_cast(unsigned, a),
            __ATOMIC_RELAXED, __HIP_MEMORY_SCOPE_AGENT);

        float run_a = 1.0f, run_b = 0.0f, c_in = 0.0f;
        int p = blk - 1;
        bool done = (blk == 0);
        while (!done) {
            const unsigned long long vi = __hip_atomic_load(&Pincl[(long)p * 64 + t],
                __ATOMIC_RELAXED, __HIP_MEMORY_SCOPE_AGENT);
            if (vi != EMPTY64) {
                c_in = fmaf(__builtin_bit_cast(float, (unsigned)(vi >> 32)), run_a, run_b);
                done = true;
            } else {
                const unsigned long long pp = __hip_atomic_load(&Ppart[(long)p * 64 + t],
                    __ATOMIC_RELAXED, __HIP_MEMORY_SCOPE_AGENT);
                if (pp != EMPTY64) {
                    const float ap = __builtin_bit_cast(float, (unsigned)pp);
                    const float bp = __builtin_bit_cast(float, (unsigned)(pp >> 32));
                    run_b = fmaf(bp, run_a, run_b);
                    run_a *= ap;
                    if (--p < 0) { c_in = run_b; done = true; }
                } else {
                    __builtin_amdgcn_s_sleep(1);
                }
            }
        }
        const float v = fmaf(c_in, a, b);
        __hip_atomic_store(&Pincl[me],
            ((unsigned long long)__builtin_bit_cast(unsigned, v) << 32) | 1ull,
            __ATOMIC_RELAXED, __HIP_MEMORY_SCOPE_AGENT);
        sCin[t] = c_in;
    }
    __syncthreads();

    // apply: 4-wave, fold preceding segment partials, p = og*c -> swizzled sP
    {
        float c = sCin[lane];
        for (int k = 0; k < w; ++k)
            c = fmaf(c, spa[(k << 6) + lane], spb[(k << 6) + lane]);
        const int cch = lane >> 3, half = lane & 7;
        #pragma unroll
        for (int r = 0; r < 16; ++r) {
            const int row = (w << 4) + r;
            const float fg = b2f(sFG[row * 72 + lane]);
            const float hr = b2f(sHR[row * 72 + lane]);
            c = fmaf(c, fg, hr);
            sP[row * 64 + ((cch ^ (row & 7)) * 8) + half] = f2b(b2f(sOG[row * 72 + lane]) * c);
        }
    }
    __syncthreads();

    // PV GEMM (verbatim R6): O_tile = p(64x64) @ WcT^T + b_c
    const int wn2 = grpB * 32;
    f32x4 acc2[2][2] = {};
    #pragma unroll
    for (int kk = 0; kk < 2; ++kk) {
        bf16x8 pa[2], wbx[2];
        #pragma unroll
        for (int i = 0; i < 2; ++i) {
            const int row = wm + i * 16 + lr, c = kk * 4 + lc;
            pa[i] = *(const bf16x8*)&sP[row * 64 + ((c ^ (row & 7)) * 8)];
        }
        #pragma unroll
        for (int j = 0; j < 2; ++j)
            wbx[j] = *(const bf16x8*)(WcT + (wn2 + j * 16 + lr) * 64 + kk * 32 + lc * 8);
        #pragma unroll
        for (int i = 0; i < 2; ++i)
            #pragma unroll
            for (int j = 0; j < 2; ++j)
                acc2[i][j] = MFMA(pa[i], wbx[j], acc2[i][j]);
    }
    #pragma unroll
    for (int i = 0; i < 2; ++i)
        #pragma unroll
        for (int j = 0; j < 2; ++j) {
            const int col = wn2 + j * 16 + lr;
            const float bv = b_c[col];
            #pragma unroll
            for (int r = 0; r < 4; ++r) {
                const int row = wm + i * 16 + (lc << 2) + r;
                O[(row0 + row) * 64 + col] = f2b(acc2[i][j][r] + bv);
            }
        }
}

// ---------------- OLD fused gate GEMM + scan (fallback for small ws) ----------------
template <int APPLY>
__global__ __launch_bounds__(256, 4)
void gates_scan(const ushort* __restrict__ X, const ushort* __restrict__ W2T,
                const float* __restrict__ b2, const ushort* __restrict__ WcT,
                const float* __restrict__ b_c,
                float* __restrict__ Agg, float* __restrict__ Bgg,
                const float* __restrict__ PreS, ushort* __restrict__ O) {
    __shared__ __align__(16) char smem[APPLY ? 35840 : 18432];
    ushort* sFG = (ushort*)smem;
    ushort* sHR = (ushort*)(smem + 9216);
    ushort* sOG = (ushort*)(smem + 18432);
    ushort* sP  = (ushort*)(smem + 27648);

    const int t = threadIdx.x, w = t >> 6, lane = t & 63;
    const int blk = blockIdx.x;
    const long row0 = (long)blk * CROWS;

    const int wm = (w >> 1) * 32;
    const int grpB = w & 1;
    const int colbase = grpB * 128;
    const int lr = lane & 15, lc = lane >> 4;

    bf16x8 af[2][2];
    #pragma unroll
    for (int kk = 0; kk < 2; ++kk)
        #pragma unroll
        for (int i = 0; i < 2; ++i)
            af[kk][i] = *(const bf16x8*)(X + (row0 + wm + i * 16 + lr) * 64 + kk * 32 + lc * 8);

    f32x4 acc[2][8] = {};
    #pragma unroll
    for (int kk = 0; kk < 2; ++kk)
        #pragma unroll
        for (int j = 0; j < 8; ++j) {
            const bf16x8 bf = *(const bf16x8*)(W2T + (colbase + j * 16 + lr) * 64 + kk * 32 + lc * 8);
            acc[0][j] = MFMA(af[kk][0], bf, acc[0][j]);
            acc[1][j] = MFMA(af[kk][1], bf, acc[1][j]);
        }

    if (!grpB) {
        #pragma unroll
        for (int jj = 0; jj < 4; ++jj) {
            const int ch = jj * 16 + lr;
            const float bi = b2[ch], bh = b2[64 + ch];
            #pragma unroll
            for (int i = 0; i < 2; ++i)
                #pragma unroll
                for (int r = 0; r < 4; ++r) {
                    const int row = wm + i * 16 + (lc << 2) + r;
                    const float gi = acc[i][jj][r] + bi;
                    const float gh = acc[i][jj + 4][r] + bh;
                    sHR[row * 72 + ch] = f2b(sigm(gi) * tanh_fast(gh));
                }
        }
    } else {
        #pragma unroll
        for (int jj = 0; jj < 4; ++jj) {
            const int ch = jj * 16 + lr;
            const float bfg = b2[128 + ch], bog = b2[192 + ch];
            #pragma unroll
            for (int i = 0; i < 2; ++i)
                #pragma unroll
                for (int r = 0; r < 4; ++r) {
                    const int row = wm + i * 16 + (lc << 2) + r;
                    sFG[row * 72 + ch] = f2b(sigm(acc[i][jj][r] + bfg));
                    if (APPLY) sOG[row * 72 + ch] = f2b(sigm(acc[i][jj + 4][r] + bog));
                }
        }
    }
    __syncthreads();

    if (!APPLY) {
        if (t < 64) {
            float a = 1.0f, b = 0.0f;
            #pragma unroll 8
            for (int r = 0; r < CROWS; ++r) {
                const float fg = b2f(sFG[r * 72 + t]);
                const float hr = b2f(sHR[r * 72 + t]);
                a *= fg;
                b = fmaf(b, fg, hr);
            }
            Agg[blk * 64 + t] = a;
            Bgg[blk * 64 + t] = b;
        }
        return;
    }

    if (t < 64) {
        float c = fmaf(PreS[(blk >> 6) * 64 + t], Agg[blk * 64 + t], Bgg[blk * 64 + t]);
        const int cch = t >> 3, half = t & 7;
        #pragma unroll 8
        for (int r = 0; r < CROWS; ++r) {
            const float fg = b2f(sFG[r * 72 + t]);
            const float hr = b2f(sHR[r * 72 + t]);
            c = fmaf(c, fg, hr);
            sP[r * 64 + ((cch ^ (r & 7)) * 8) + half] = f2b(b2f(sOG[r * 72 + t]) * c);
        }
    }
    __syncthreads();

    const int wn2 = grpB * 32;
    f32x4 acc2[2][2] = {};
    #pragma unroll
    for (int kk = 0; kk < 2; ++kk) {
        bf16x8 pa[2], wbx[2];
        #pragma unroll
        for (int i = 0; i < 2; ++i) {
            const int row = wm + i * 16 + lr, c = kk * 4 + lc;
            pa[i] = *(const bf16x8*)&sP[row * 64 + ((c ^ (row & 7)) * 8)];
        }
        #pragma unroll
        for (int j = 0; j < 2; ++j)
            wbx[j] = *(const bf16x8*)(WcT + (wn2 + j * 16 + lr) * 64 + kk * 32 + lc * 8);
        #pragma unroll
        for (int i = 0; i < 2; ++i)
            #pragma unroll
            for (int j = 0; j < 2; ++j)
                acc2[i][j] = MFMA(pa[i], wbx[j], acc2[i][j]);
    }
    #pragma unroll
    for (int i = 0; i < 2; ++i)
        #pragma unroll
        for (int j = 0; j < 2; ++j) {
            const int col = wn2 + j * 16 + lr;
            const float bv = b_c[col];
            #pragma unroll
            for (int r = 0; r < 4; ++r) {
                const int row = wm + i * 16 + (lc << 2) + r;
                O[(row0 + row) * 64 + col] = f2b(acc2[i][j][r] + bv);
            }
        }
}

// ---------------- two-level prefix combine (fallback path only) ----------------
__global__ void scan_super(float* __restrict__ Agg, float* __restrict__ Bgg,
                           float* __restrict__ SA, float* __restrict__ SB) {
    const int s = blockIdx.x, ch = threadIdx.x;
    float a = 1.0f, b = 0.0f;
    #pragma unroll 8
    for (int j = 0; j < 64; ++j) {
        const int idx = (s * 64 + j) * 64 + ch;
        const float a2 = Agg[idx], bb = Bgg[idx];
        Agg[idx] = a;
        Bgg[idx] = b;
        a *= a2;
        b = fmaf(b, a2, bb);
    }
    SA[s * 64 + ch] = a;
    SB[s * 64 + ch] = b;
}

__global__ void scan_top(const float* __restrict__ SA, const float* __restrict__ SB,
                         float* __restrict__ PreS) {
    const int ch = threadIdx.x;
    float c = 0.0f;
    #pragma unroll 8
    for (int s = 0; s < 64; ++s) {
        PreS[s * 64 + ch] = c;
        c = fmaf(c, SA[s * 64 + ch], SB[s * 64 + ch]);
    }
}

// ---------------- launch ----------------
extern "C" void kernel_launch(void* const* d_in, const int* in_sizes, int n_in,
                              void* d_out, int out_size, void* d_ws, size_t ws_size,
                              hipStream_t stream) {
    const float* inputs  = (const float*)d_in[0];
    const float* W_in    = (const float*)d_in[1];
    const float* b_in    = (const float*)d_in[2];
    const float* W_gates = (const float*)d_in[3];
    const float* b_gates = (const float*)d_in[4];
    const float* W_og    = (const float*)d_in[5];
    const float* b_og    = (const float*)d_in[6];
    const float* W_c     = (const float*)d_in[7];
    const float* b_c     = (const float*)d_in[8];
    const float* W_out   = (const float*)d_in[9];
    const float* b_out   = (const float*)d_in[10];
    float* out = (float*)d_out;

    char* ws = (char*)d_ws;
    ushort* X     = (ushort*)(ws);                   // 33554432 B (O in-place)
    ushort* WinT  = (ushort*)(ws + 33554432);        // 524288
    ushort* WoutT = (ushort*)(ws + 34078720);        // 524288
    ushort* W2T   = (ushort*)(ws + 34603008);        // 32768
    ushort* WcT   = (ushort*)(ws + 34635776);        // 8192
    float*  b2    = (float*)(ws + 34643968);         // 1024
    float*  Agg   = (float*)(ws + 34644992);         // 1048576 (fallback)
    float*  Bgg   = (float*)(ws + 35693568);         // 1048576 (fallback)
    float*  SA    = (float*)(ws + 36742144);         // 16384   (fallback)
    float*  SB    = (float*)(ws + 36758528);         // 16384   (fallback)
    float*  PreS  = (float*)(ws + 36774912);         // 16384   (fallback)
    ushort* Ibf   = (ushort*)(ws + 36791296);        // 33554432, ends 70345728
    unsigned long long* Ppart = (unsigned long long*)(ws + 70345728);  // 2 MB
    unsigned long long* Pincl = (unsigned long long*)(ws + 72442880);  // 2 MB, end 74539008
    ushort* O = X;

    const bool lb_ws  = ws_size >= 74539008ull;      // lookback state fits
    const bool big_ws = ws_size >= 70345728ull;      // Ibf fits

    transpose512<<<dim3(16, 16), 256, 0, stream>>>(W_in, WinT);
    transpose512<<<dim3(16, 16), 256, 0, stream>>>(W_out, WoutT);
    prep_small<<<81, 256, 0, stream>>>(W_gates, W_og, W_c, b_gates, b_og, W2T, WcT, b2);

    if (lb_ws) {
        cvt_f32_bf16<<<8192, 256, 0, stream>>>(inputs, Ibf, Ppart, Pincl);
        gemm_bt<128, 128, 2, 2, 0, 0><<<dim3(256, 4), 256, 0, stream>>>(
            Ibf, WinT, b_in, X, 32768, 512, 512);
        gates_fused<<<NCH, 256, 0, stream>>>(X, W2T, b2, WcT, b_c, Ppart, Pincl, O);
    } else if (big_ws) {
        cvt_f32_bf16<<<8192, 256, 0, stream>>>(inputs, Ibf, nullptr, nullptr);
        gemm_bt<128, 128, 2, 2, 0, 0><<<dim3(256, 4), 256, 0, stream>>>(
            Ibf, WinT, b_in, X, 32768, 512, 512);
        gates_scan<0><<<NCH, 256, 0, stream>>>(X, W2T, b2, WcT, b_c, Agg, Bgg, PreS, O);
        scan_super<<<NSUP, 64, 0, stream>>>(Agg, Bgg, SA, SB);
        scan_top<<<1, 64, 0, stream>>>(SA, SB, PreS);
        gates_scan<1><<<NCH, 256, 0, stream>>>(X, W2T, b2, WcT, b_c, Agg, Bgg, PreS, O);
    } else {
        gemm_bt<128, 128, 2, 2, 1, 0><<<dim3(256, 4), 256, 0, stream>>>(
            inputs, WinT, b_in, X, 32768, 512, 512);
        gates_scan<0><<<NCH, 256, 0, stream>>>(X, W2T, b2, WcT, b_c, Agg, Bgg, PreS, O);
        scan_super<<<NSUP, 64, 0, stream>>>(Agg, Bgg, SA, SB);
        scan_top<<<1, 64, 0, stream>>>(SA, SB, PreS);
        gates_scan<1><<<NCH, 256, 0, stream>>>(X, W2T, b2, WcT, b_c, Agg, Bgg, PreS, O);
    }

    gemm_bt<128, 128, 2, 2, 0, 1><<<dim3(256, 4), 256, 0, stream>>>(
        O, WoutT, b_out, out, 32768, 512, 512);
}